// Round 6
// baseline (55.965 us; speedup 1.0000x reference)
//
#include <hip/hip_runtime.h>

constexpr int B = 64, N = 8732, C = 21, M = 16;
constexpr int BN = B * N;             // 558848
constexpr int TROW = 1 + 6 * M;       // 97
constexpr int NB1 = 2048;             // level-1 bins (key >> 21)
constexpr int NB2 = 4096;             // level-2 bins (key >> 9) & 0xFFF
constexpr int NSLAB = 32;             // level-1 slab replicas
constexpr int R2 = 2;                 // level-2 replicas
constexpr int ROWS_PB = 256;
constexpr int BPB = (N + ROWS_PB - 1) / ROWS_PB;  // 35
constexpr int P2B = 64;               // pass2 blocks (= B; BN/P2B = 8732 exact)
constexpr int KPB = BN / P2B;         // 8732 keys per pass2 block
constexpr float FSCALE = 262144.0f;   // 2^18
constexpr unsigned long long CNT1 = 1ull << 44;
constexpr unsigned long long FIXMASK = (1ull << 44) - 1;

struct Ctl2 {
  unsigned flag;       // 0 until scan1 done; then t1+1
  unsigned doneCnt;
  unsigned r1;
  unsigned pad;
  unsigned long long fixBelow1;
  float pnum, validCnt, posCE, bboxNum;
};

__device__ __forceinline__ unsigned f2key(float f) {
  unsigned u = __float_as_uint(f);
  return (u & 0x80000000u) ? ~u : (u | 0x80000000u);
}
__device__ __forceinline__ float key2f(unsigned k) {
  unsigned u = (k & 0x80000000u) ? (k ^ 0x80000000u) : ~k;
  return __uint_as_float(u);
}

// ---- zero slabs + merged2 + batchCtl + ctl (contiguous region) ----
__global__ __launch_bounds__(256) void k_zero(unsigned long long* __restrict__ z,
                                              int nz) {
  int gid = blockIdx.x * 256 + threadIdx.x;
  for (int i = gid; i < nz; i += 96 * 256) z[i] = 0ull;
}

// ---- main: logp0 -> keys + LDS hist -> slab merge; fused targets ----
__global__ __launch_bounds__(256) void k_main(
    const float* __restrict__ conf, const float* __restrict__ bbox,
    const float* __restrict__ target, const float* __restrict__ pred,
    unsigned* __restrict__ keys, unsigned long long* __restrict__ slab1,
    float4* __restrict__ batchCtl) {
  __shared__ __align__(16) float srow[ROWS_PB * C];      // 21504 B
  __shared__ unsigned long long shist[NB1];              // 16384 B
  __shared__ int sk[M];
  int b = blockIdx.y, bx = blockIdx.x, tid = threadIdx.x;

  for (int i = tid; i < NB1; i += 256) shist[i] = 0ull;
  const float* tr = target + (size_t)b * TROW;
  if (tid < M) {
    int num = (int)tr[0];
    sk[tid] = (tid < num) ? (int)tr[1 + 6 * tid + 5] : -1;
  }
  __syncthreads();

  int n0 = bx * ROWS_PB;
  int rows = min(ROWS_PB, N - n0);
  const float* g = conf + ((size_t)b * N + n0) * C;
  int nf = rows * C;
  int nf4 = nf >> 2;
  const float4* g4 = (const float4*)g;
  float4* s4 = (float4*)srow;
  for (int i = tid; i < nf4; i += 256) s4[i] = g4[i];
  for (int i = nf4 * 4 + tid; i < nf; i += 256) srow[i] = g[i];
  __syncthreads();

  if (tid < rows) {
    int n = n0 + tid;
    const float* x = srow + tid * C;
    float mx = x[0];
    for (int c = 1; c < C; c++) mx = fmaxf(mx, x[c]);
    float sum = 0.f;
    for (int c = 0; c < C; c++) sum += __expf(x[c] - mx);
    float logp0 = x[0] - mx - __logf(sum);
    bool asg = false;
    for (int j = 0; j < M; j++) asg |= (sk[j] == n);
    unsigned key = 0xFFFFFFFFu;
    if (!asg) {
      key = f2key(logp0);
      float ce = -logp0;
      atomicAdd(&shist[key >> 21],
                CNT1 | (unsigned long long)(ce * FSCALE + 0.5f));
    }
    keys[(size_t)b * N + n] = key;
  }
  __syncthreads();

  unsigned long long* sg = slab1 + ((size_t)((b * BPB + bx) & (NSLAB - 1)) * NB1);
  for (int i = tid; i < NB1; i += 256) {
    unsigned long long v = shist[i];
    if (v) atomicAdd(&sg[i], v);
  }

  if (bx == 0) {
    float myValid = 0.f, myPos = 0.f, myCE = 0.f, mySL = 0.f;
    if (tid < M && sk[tid] >= 0) {
      const float* e = tr + 1 + 6 * tid;
      int cls = (int)e[0];
      float tx1 = e[1], ty1 = e[2], tx2 = e[3], ty2 = e[4];
      int k = sk[tid];
      float p0 = pred[k * 4 + 0], p1 = pred[k * 4 + 1];
      float p2 = pred[k * 4 + 2], p3 = pred[k * 4 + 3];
      float pw = p2 - p0, ph = p3 - p1;
      float pcx = (p0 + p2) * 0.5f, pcy = (p1 + p3) * 0.5f;
      float tw = tx2 - tx1, th = ty2 - ty1;
      float tcx = (tx1 + tx2) * 0.5f, tcy = (ty1 + ty2) * 0.5f;
      float ebv[4];
      ebv[0] = (tcx - pcx) / pw;
      ebv[1] = (tcy - pcy) / ph;
      ebv[2] = __logf(tw / pw);
      ebv[3] = __logf(th / ph);
      const float* bo = bbox + ((size_t)b * N + k) * 4;
      float sl = 0.f;
      for (int j = 0; j < 4; j++) {
        float d = bo[j] - ebv[j];
        float ad = fabsf(d);
        sl += (ad < 1.f) ? 0.5f * d * d : ad - 0.5f;
      }
      myValid = 1.f; mySL = sl;
      if (cls > 0) {
        const float* x = conf + ((size_t)b * N + k) * C;
        float mx = x[0];
        for (int c = 1; c < C; c++) mx = fmaxf(mx, x[c]);
        float s = 0.f;
        for (int c = 0; c < C; c++) s += __expf(x[c] - mx);
        float lp = x[cls] - mx - __logf(s);
        myPos = 1.f; myCE = -lp;
      }
    }
    if (tid < 64) {
      for (int off = 32; off; off >>= 1) {
        myValid += __shfl_down(myValid, off, 64);
        myPos   += __shfl_down(myPos, off, 64);
        myCE    += __shfl_down(myCE, off, 64);
        mySL    += __shfl_down(mySL, off, 64);
      }
      if (tid == 0) batchCtl[b] = make_float4(myPos, myValid, myCE, mySL);
    }
  }
}

// ---- pass2: block0 scan1 -> flag; all blocks stash keys, filter, merge;
// ---- last block does final scan + writes outputs. Single dispatch. ----
__global__ __launch_bounds__(256) void k_pass2(
    const unsigned* __restrict__ keys,
    const unsigned long long* __restrict__ slab1,
    const float4* __restrict__ batchCtl,
    unsigned long long* __restrict__ merged2,
    Ctl2* __restrict__ ctl, float* __restrict__ out) {
  __shared__ __align__(16) unsigned skeys[KPB];            // 34928 B
  __shared__ __align__(16) unsigned long long lh[NB2];     // 32768 B
  __shared__ unsigned sT1, sLast;
  __shared__ double sNeg;
  int tid = threadIdx.x, blk = blockIdx.x;

  if (blk == 0) {
    // --- scan1 duties (uses lh[0..2047] and skeys[0..511] as scratch) ---
    float p = 0.f, va = 0.f, ce = 0.f, sl = 0.f;
    if (tid < 64) {
      float4 v = batchCtl[tid];
      p = v.x; va = v.y; ce = v.z; sl = v.w;
      for (int off = 32; off; off >>= 1) {
        p  += __shfl_down(p, off, 64);
        va += __shfl_down(va, off, 64);
        ce += __shfl_down(ce, off, 64);
        sl += __shfl_down(sl, off, 64);
      }
    }
    unsigned long long* sm = lh;
    for (int j = 0; j < NB1 / 256; j++) {
      int bin = tid + j * 256;
      unsigned long long v = 0ull;
      for (int s = 0; s < NSLAB; s++) v += slab1[(size_t)s * NB1 + bin];
      sm[bin] = v;
    }
    __shared__ unsigned srank; __shared__ float sp, sva, sce, ssl;
    __shared__ unsigned st1, sr1; __shared__ unsigned long long sfix;
    if (tid == 0) {
      sp = p; sva = va; sce = ce; ssl = sl;
      srank = 3u * (unsigned)(p + 0.5f);
      st1 = 0xFFFFu; sr1 = 0; sfix = 0ull;
    }
    __syncthreads();
    unsigned long long* sscan = (unsigned long long*)skeys;
    unsigned long long part = 0ull;
    for (int j = 0; j < 8; j++) part += sm[tid * 8 + j];
    sscan[tid] = part;
    __syncthreads();
    for (int off = 1; off < 256; off <<= 1) {
      unsigned long long add = (tid >= off) ? sscan[tid - off] : 0ull;
      __syncthreads();
      sscan[tid] += add;
      __syncthreads();
    }
    unsigned rank = srank;
    if (rank) {
      unsigned long long cum = sscan[tid] - part;
      for (int j = 0; j < 8; j++) {
        unsigned long long h = sm[tid * 8 + j];
        unsigned c0 = (unsigned)(cum >> 44);
        unsigned c1 = (unsigned)((cum + h) >> 44);
        if (c0 < rank && c1 >= rank) { st1 = tid * 8 + j; sr1 = rank - c0; sfix = cum & FIXMASK; }
        cum += h;
      }
    }
    __syncthreads();
    if (tid == 0) {
      ctl->r1 = sr1; ctl->fixBelow1 = sfix;
      ctl->pnum = sp; ctl->validCnt = sva; ctl->posCE = sce; ctl->bboxNum = ssl;
      __hip_atomic_store(&ctl->flag, st1 + 1u, __ATOMIC_RELEASE, __HIP_MEMORY_SCOPE_AGENT);
    }
    __syncthreads();
  }

  // --- all blocks: zero lh, stash this block's key slice into LDS ---
  for (int i = tid; i < NB2; i += 256) lh[i] = 0ull;
  {
    const uint4* src = (const uint4*)(keys + (size_t)blk * KPB);
    uint4* dst = (uint4*)skeys;
    for (int i = tid; i < KPB / 4; i += 256) dst[i] = src[i];
  }
  if (tid == 0) {
    unsigned fv;
    do {
      fv = __hip_atomic_load(&ctl->flag, __ATOMIC_ACQUIRE, __HIP_MEMORY_SCOPE_AGENT);
      if (!fv) __builtin_amdgcn_s_sleep(8);
    } while (!fv);
    sT1 = fv - 1u;
  }
  __syncthreads();
  unsigned t1 = sT1;

  // --- filter from LDS stash into lh ---
  for (int i = tid; i < KPB; i += 256) {
    unsigned key = skeys[i];
    if ((key >> 21) == t1) {
      float ce = -key2f(key);
      atomicAdd(&lh[(key >> 9) & 0xFFFu],
                CNT1 | (unsigned long long)(ce * FSCALE + 0.5f));
    }
  }
  __syncthreads();
  unsigned long long* mg = merged2 + (size_t)(blk & (R2 - 1)) * NB2;
  for (int i = tid; i < NB2; i += 256) {
    unsigned long long v = lh[i];
    if (v) atomicAdd(&mg[i], v);
  }
  __syncthreads();
  if (tid == 0) {
    unsigned r = __hip_atomic_fetch_add(&ctl->doneCnt, 1u, __ATOMIC_ACQ_REL,
                                        __HIP_MEMORY_SCOPE_AGENT);
    sLast = (r == P2B - 1) ? 1u : 0u;
  }
  __syncthreads();
  if (!sLast) return;

  // --- final: last block scans merged2 (atomic loads), writes outputs ---
  unsigned long long* sm = lh;
  for (int k2 = 0; k2 < NB2 / 256; k2++) {
    int bin = tid + k2 * 256;
    unsigned long long v =
        __hip_atomic_load(&merged2[bin], __ATOMIC_RELAXED, __HIP_MEMORY_SCOPE_AGENT) +
        __hip_atomic_load(&merged2[NB2 + bin], __ATOMIC_RELAXED, __HIP_MEMORY_SCOPE_AGENT);
    sm[bin] = v;
  }
  if (tid == 0) sNeg = 0.0;
  __syncthreads();
  unsigned long long* sscan2 = (unsigned long long*)skeys;
  unsigned long long part = 0ull;
  for (int j = 0; j < 16; j++) part += sm[tid * 16 + j];
  sscan2[tid] = part;
  __syncthreads();
  for (int off = 1; off < 256; off <<= 1) {
    unsigned long long add = (tid >= off) ? sscan2[tid - off] : 0ull;
    __syncthreads();
    sscan2[tid] += add;
    __syncthreads();
  }
  unsigned r1v = __hip_atomic_load(&ctl->r1, __ATOMIC_RELAXED, __HIP_MEMORY_SCOPE_AGENT);
  unsigned long long fixB1 = __hip_atomic_load(&ctl->fixBelow1, __ATOMIC_RELAXED, __HIP_MEMORY_SCOPE_AGENT);
  float pnumv = __hip_atomic_load(&ctl->pnum, __ATOMIC_RELAXED, __HIP_MEMORY_SCOPE_AGENT);
  float svalid = __hip_atomic_load(&ctl->validCnt, __ATOMIC_RELAXED, __HIP_MEMORY_SCOPE_AGENT);
  float posCEv = __hip_atomic_load(&ctl->posCE, __ATOMIC_RELAXED, __HIP_MEMORY_SCOPE_AGENT);
  float bboxv  = __hip_atomic_load(&ctl->bboxNum, __ATOMIC_RELAXED, __HIP_MEMORY_SCOPE_AGENT);
  if (r1v) {
    unsigned long long cum = sscan2[tid] - part;
    for (int j = 0; j < 16; j++) {
      unsigned long long h = sm[tid * 16 + j];
      unsigned c0 = (unsigned)(cum >> 44);
      unsigned c1 = (unsigned)((cum + h) >> 44);
      if (c0 < r1v && c1 >= r1v) {
        unsigned t2 = tid * 16 + j;
        unsigned r2v = r1v - c0;
        unsigned long long fixB2 = cum & FIXMASK;
        float ceEdge = -key2f((t1 << 21) | (t2 << 9));
        sNeg = (double)(fixB1 + fixB2) / 262144.0 + (double)r2v * (double)ceEdge;
      }
      cum += h;
    }
  }
  __syncthreads();
  if (tid == 0) {
    out[0] = (posCEv + (float)sNeg) / fmaxf(4.0f * pnumv, 1.0f);
    out[1] = bboxv / fmaxf(4.0f * svalid, 1.0f);
  }
}

extern "C" void kernel_launch(void* const* d_in, const int* in_sizes, int n_in,
                              void* d_out, int out_size, void* d_ws, size_t ws_size,
                              hipStream_t stream) {
  const float* conf = (const float*)d_in[0];
  const float* bbox = (const float*)d_in[1];
  const float* target = (const float*)d_in[2];
  const float* pred = (const float*)d_in[3];
  float* out = (float*)d_out;

  char* ws = (char*)d_ws;
  unsigned* keys = (unsigned*)ws;
  size_t off = (size_t)BN * 4;                                   // 2,235,392
  size_t zbase = off;
  unsigned long long* slab1 = (unsigned long long*)(ws + off); off += (size_t)NSLAB * NB1 * 8;
  unsigned long long* merged2 = (unsigned long long*)(ws + off); off += (size_t)R2 * NB2 * 8;
  float4* batchCtl = (float4*)(ws + off); off += 64 * 16;
  Ctl2* ctl = (Ctl2*)(ws + off); off += 64;
  int nz = (int)((off - zbase) / 8);

  k_zero<<<96, 256, 0, stream>>>((unsigned long long*)(ws + zbase), nz);
  k_main<<<dim3(BPB, B), 256, 0, stream>>>(conf, bbox, target, pred, keys, slab1, batchCtl);
  k_pass2<<<P2B, 256, 0, stream>>>(keys, slab1, batchCtl, merged2, ctl, out);
}

// Round 7
// 49.944 us; speedup vs baseline: 1.1206x; 1.1206x over previous
//
#include <hip/hip_runtime.h>

constexpr int B = 64, N = 8732, C = 21, M = 16;
constexpr int BN = B * N;             // 558848
constexpr int TROW = 1 + 6 * M;       // 97
constexpr int NB1 = 2048;             // level-1 bins (key >> 21)
constexpr int NB2 = 4096;             // level-2 bins (key >> 9) & 0xFFF
constexpr int NSLAB = 8;              // level-1 slab replicas
constexpr int R2 = 2;                 // level-2 replicas
constexpr int ROWS_PB = 256;
constexpr int BPB = (N + ROWS_PB - 1) / ROWS_PB;  // 35
constexpr int P2B = 64;               // pass2 blocks; BN/P2B = 8732 exact
constexpr int KPB = BN / P2B;         // 8732 keys per pass2 block
constexpr int BINS_PER_BLK = NB1 / P2B;  // 32
constexpr float FSCALE = 262144.0f;   // 2^18
constexpr unsigned long long CNT1 = 1ull << 44;
constexpr unsigned long long FIXMASK = (1ull << 44) - 1;

struct Ctl2 {
  unsigned flag;       // 0 until scan1 done; then t1+1
  unsigned doneCnt1;   // cooperative-reduce completion counter
  unsigned doneCnt2;   // filter/merge completion counter
  unsigned r1;
  unsigned long long fixBelow1;
  float pnum, validCnt, posCE, bboxNum;
};

__device__ __forceinline__ unsigned f2key(float f) {
  unsigned u = __float_as_uint(f);
  return (u & 0x80000000u) ? ~u : (u | 0x80000000u);
}
__device__ __forceinline__ float key2f(unsigned k) {
  unsigned u = (k & 0x80000000u) ? (k ^ 0x80000000u) : ~k;
  return __uint_as_float(u);
}

// ---- zero slabs + merged1 + merged2 + ctl (contiguous region) ----
__global__ __launch_bounds__(256) void k_zero(unsigned long long* __restrict__ z,
                                              int nz) {
  int gid = blockIdx.x * 256 + threadIdx.x;
  for (int i = gid; i < nz; i += 64 * 256) z[i] = 0ull;
}

// ---- main: logp0 -> keys + LDS hist -> slab merge; fused targets ----
__global__ __launch_bounds__(256) void k_main(
    const float* __restrict__ conf, const float* __restrict__ bbox,
    const float* __restrict__ target, const float* __restrict__ pred,
    unsigned* __restrict__ keys, unsigned long long* __restrict__ slab1,
    float4* __restrict__ batchCtl) {
  __shared__ __align__(16) float srow[ROWS_PB * C];      // 21504 B
  __shared__ unsigned long long shist[NB1];              // 16384 B
  __shared__ int sk[M];
  int b = blockIdx.y, bx = blockIdx.x, tid = threadIdx.x;

  for (int i = tid; i < NB1; i += 256) shist[i] = 0ull;
  const float* tr = target + (size_t)b * TROW;
  if (tid < M) {
    int num = (int)tr[0];
    sk[tid] = (tid < num) ? (int)tr[1 + 6 * tid + 5] : -1;
  }
  __syncthreads();

  int n0 = bx * ROWS_PB;
  int rows = min(ROWS_PB, N - n0);
  const float* g = conf + ((size_t)b * N + n0) * C;
  int nf = rows * C;
  int nf4 = nf >> 2;
  const float4* g4 = (const float4*)g;
  float4* s4 = (float4*)srow;
  for (int i = tid; i < nf4; i += 256) s4[i] = g4[i];
  for (int i = nf4 * 4 + tid; i < nf; i += 256) srow[i] = g[i];
  __syncthreads();

  if (tid < rows) {
    int n = n0 + tid;
    const float* x = srow + tid * C;
    float mx = x[0];
    for (int c = 1; c < C; c++) mx = fmaxf(mx, x[c]);
    float sum = 0.f;
    for (int c = 0; c < C; c++) sum += __expf(x[c] - mx);
    float logp0 = x[0] - mx - __logf(sum);
    bool asg = false;
    for (int j = 0; j < M; j++) asg |= (sk[j] == n);
    unsigned key = 0xFFFFFFFFu;
    if (!asg) {
      key = f2key(logp0);
      float ce = -logp0;
      atomicAdd(&shist[key >> 21],
                CNT1 | (unsigned long long)(ce * FSCALE + 0.5f));
    }
    keys[(size_t)b * N + n] = key;
  }
  __syncthreads();

  unsigned long long* sg = slab1 + ((size_t)((b * BPB + bx) & (NSLAB - 1)) * NB1);
  for (int i = tid; i < NB1; i += 256) {
    unsigned long long v = shist[i];
    if (v) atomicAdd(&sg[i], v);
  }

  if (bx == 0) {
    float myValid = 0.f, myPos = 0.f, myCE = 0.f, mySL = 0.f;
    if (tid < M && sk[tid] >= 0) {
      const float* e = tr + 1 + 6 * tid;
      int cls = (int)e[0];
      float tx1 = e[1], ty1 = e[2], tx2 = e[3], ty2 = e[4];
      int k = sk[tid];
      float p0 = pred[k * 4 + 0], p1 = pred[k * 4 + 1];
      float p2 = pred[k * 4 + 2], p3 = pred[k * 4 + 3];
      float pw = p2 - p0, ph = p3 - p1;
      float pcx = (p0 + p2) * 0.5f, pcy = (p1 + p3) * 0.5f;
      float tw = tx2 - tx1, th = ty2 - ty1;
      float tcx = (tx1 + tx2) * 0.5f, tcy = (ty1 + ty2) * 0.5f;
      float ebv[4];
      ebv[0] = (tcx - pcx) / pw;
      ebv[1] = (tcy - pcy) / ph;
      ebv[2] = __logf(tw / pw);
      ebv[3] = __logf(th / ph);
      const float* bo = bbox + ((size_t)b * N + k) * 4;
      float sl = 0.f;
      for (int j = 0; j < 4; j++) {
        float d = bo[j] - ebv[j];
        float ad = fabsf(d);
        sl += (ad < 1.f) ? 0.5f * d * d : ad - 0.5f;
      }
      myValid = 1.f; mySL = sl;
      if (cls > 0) {
        const float* x = conf + ((size_t)b * N + k) * C;
        float mx = x[0];
        for (int c = 1; c < C; c++) mx = fmaxf(mx, x[c]);
        float s = 0.f;
        for (int c = 0; c < C; c++) s += __expf(x[c] - mx);
        float lp = x[cls] - mx - __logf(s);
        myPos = 1.f; myCE = -lp;
      }
    }
    if (tid < 64) {
      for (int off = 32; off; off >>= 1) {
        myValid += __shfl_down(myValid, off, 64);
        myPos   += __shfl_down(myPos, off, 64);
        myCE    += __shfl_down(myCE, off, 64);
        mySL    += __shfl_down(mySL, off, 64);
      }
      if (tid == 0) batchCtl[b] = make_float4(myPos, myValid, myCE, mySL);
    }
  }
}

// ---- pass2 (single dispatch): cooperative slab reduce -> last block scans ->
// ---- all filter LDS-stashed keys -> merge -> last block finalizes. ----
__global__ __launch_bounds__(256) void k_pass2(
    const unsigned* __restrict__ keys,
    const unsigned long long* __restrict__ slab1,
    const float4* __restrict__ batchCtl,
    unsigned long long* __restrict__ merged1,
    unsigned long long* __restrict__ merged2,
    Ctl2* __restrict__ ctl, float* __restrict__ out) {
  __shared__ __align__(16) unsigned skeys[KPB];            // 34928 B
  __shared__ __align__(16) unsigned long long lh[NB2];     // 32768 B
  __shared__ unsigned long long scr[256];                  // scan scratch
  __shared__ unsigned sT1, sLast;
  __shared__ double sNeg;
  int tid = threadIdx.x, blk = blockIdx.x;

  // zero local hist + stash this block's key slice into LDS (latency overlaps
  // everything up to the filter phase)
  for (int i = tid; i < NB2; i += 256) lh[i] = 0ull;
  {
    const uint4* src = (const uint4*)(keys + (size_t)blk * KPB);
    uint4* dst = (uint4*)skeys;
    for (int i = tid; i < KPB / 4; i += 256) dst[i] = src[i];
  }

  // cooperative slab reduce: this block's 32 bins
  if (tid < BINS_PER_BLK) {
    int bin = blk * BINS_PER_BLK + tid;
    unsigned long long v = 0ull;
    for (int s = 0; s < NSLAB; s++) v += slab1[(size_t)s * NB1 + bin];
    merged1[bin] = v;
  }
  __syncthreads();
  if (tid == 0) {
    unsigned r = __hip_atomic_fetch_add(&ctl->doneCnt1, 1u, __ATOMIC_ACQ_REL,
                                        __HIP_MEMORY_SCOPE_AGENT);
    sLast = (r == P2B - 1) ? 1u : 0u;
  }
  __syncthreads();

  if (sLast) {
    // --- scan1: reduce batchCtl, scan merged1 (16 KB, L2-warm) ---
    float p = 0.f, va = 0.f, ce = 0.f, sl = 0.f;
    if (tid < 64) {
      float4 v = batchCtl[tid];
      p = v.x; va = v.y; ce = v.z; sl = v.w;
      for (int off = 32; off; off >>= 1) {
        p  += __shfl_down(p, off, 64);
        va += __shfl_down(va, off, 64);
        ce += __shfl_down(ce, off, 64);
        sl += __shfl_down(sl, off, 64);
      }
    }
    __shared__ unsigned srank; __shared__ float sp, sva, sce, ssl;
    __shared__ unsigned st1, sr1; __shared__ unsigned long long sfix;
    if (tid == 0) {
      sp = p; sva = va; sce = ce; ssl = sl;
      srank = 3u * (unsigned)(p + 0.5f);
      st1 = 0xFFFFu; sr1 = 0; sfix = 0ull;
    }
    __syncthreads();
    unsigned long long h8[8];
    unsigned long long part = 0ull;
    for (int j = 0; j < 8; j++) {
      h8[j] = __hip_atomic_load(&merged1[tid * 8 + j], __ATOMIC_RELAXED,
                                __HIP_MEMORY_SCOPE_AGENT);
      part += h8[j];
    }
    scr[tid] = part;
    __syncthreads();
    for (int off = 1; off < 256; off <<= 1) {
      unsigned long long add = (tid >= off) ? scr[tid - off] : 0ull;
      __syncthreads();
      scr[tid] += add;
      __syncthreads();
    }
    unsigned rank = srank;
    if (rank) {
      unsigned long long cum = scr[tid] - part;
      for (int j = 0; j < 8; j++) {
        unsigned long long h = h8[j];
        unsigned c0 = (unsigned)(cum >> 44);
        unsigned c1 = (unsigned)((cum + h) >> 44);
        if (c0 < rank && c1 >= rank) { st1 = tid * 8 + j; sr1 = rank - c0; sfix = cum & FIXMASK; }
        cum += h;
      }
    }
    __syncthreads();
    if (tid == 0) {
      ctl->r1 = sr1; ctl->fixBelow1 = sfix;
      ctl->pnum = sp; ctl->validCnt = sva; ctl->posCE = sce; ctl->bboxNum = ssl;
      __hip_atomic_store(&ctl->flag, st1 + 1u, __ATOMIC_RELEASE, __HIP_MEMORY_SCOPE_AGENT);
    }
  }

  if (tid == 0) {
    unsigned fv;
    do {
      fv = __hip_atomic_load(&ctl->flag, __ATOMIC_ACQUIRE, __HIP_MEMORY_SCOPE_AGENT);
      if (!fv) __builtin_amdgcn_s_sleep(2);
    } while (!fv);
    sT1 = fv - 1u;
  }
  __syncthreads();
  unsigned t1 = sT1;

  // --- filter from LDS stash into lh ---
  for (int i = tid; i < KPB; i += 256) {
    unsigned key = skeys[i];
    if ((key >> 21) == t1) {
      float ce = -key2f(key);
      atomicAdd(&lh[(key >> 9) & 0xFFFu],
                CNT1 | (unsigned long long)(ce * FSCALE + 0.5f));
    }
  }
  __syncthreads();
  unsigned long long* mg = merged2 + (size_t)(blk & (R2 - 1)) * NB2;
  for (int i = tid; i < NB2; i += 256) {
    unsigned long long v = lh[i];
    if (v) atomicAdd(&mg[i], v);
  }
  __syncthreads();
  if (tid == 0) {
    unsigned r = __hip_atomic_fetch_add(&ctl->doneCnt2, 1u, __ATOMIC_ACQ_REL,
                                        __HIP_MEMORY_SCOPE_AGENT);
    sLast = (r == P2B - 1) ? 1u : 0u;
  }
  __syncthreads();
  if (!sLast) return;

  // --- final: last block scans merged2, writes outputs ---
  unsigned long long* sm = lh;
  for (int k2 = 0; k2 < NB2 / 256; k2++) {
    int bin = tid + k2 * 256;
    unsigned long long v =
        __hip_atomic_load(&merged2[bin], __ATOMIC_RELAXED, __HIP_MEMORY_SCOPE_AGENT) +
        __hip_atomic_load(&merged2[NB2 + bin], __ATOMIC_RELAXED, __HIP_MEMORY_SCOPE_AGENT);
    sm[bin] = v;
  }
  if (tid == 0) sNeg = 0.0;
  __syncthreads();
  unsigned long long part = 0ull;
  for (int j = 0; j < 16; j++) part += sm[tid * 16 + j];
  scr[tid] = part;
  __syncthreads();
  for (int off = 1; off < 256; off <<= 1) {
    unsigned long long add = (tid >= off) ? scr[tid - off] : 0ull;
    __syncthreads();
    scr[tid] += add;
    __syncthreads();
  }
  unsigned r1v = ctl->r1;
  unsigned long long fixB1 = ctl->fixBelow1;
  float pnumv = ctl->pnum, svalid = ctl->validCnt;
  float posCEv = ctl->posCE, bboxv = ctl->bboxNum;
  if (r1v) {
    unsigned long long cum = scr[tid] - part;
    for (int j = 0; j < 16; j++) {
      unsigned long long h = sm[tid * 16 + j];
      unsigned c0 = (unsigned)(cum >> 44);
      unsigned c1 = (unsigned)((cum + h) >> 44);
      if (c0 < r1v && c1 >= r1v) {
        unsigned t2 = tid * 16 + j;
        unsigned r2v = r1v - c0;
        unsigned long long fixB2 = cum & FIXMASK;
        float ceEdge = -key2f((t1 << 21) | (t2 << 9));
        sNeg = (double)(fixB1 + fixB2) / 262144.0 + (double)r2v * (double)ceEdge;
      }
      cum += h;
    }
  }
  __syncthreads();
  if (tid == 0) {
    out[0] = (posCEv + (float)sNeg) / fmaxf(4.0f * pnumv, 1.0f);
    out[1] = bboxv / fmaxf(4.0f * svalid, 1.0f);
  }
}

extern "C" void kernel_launch(void* const* d_in, const int* in_sizes, int n_in,
                              void* d_out, int out_size, void* d_ws, size_t ws_size,
                              hipStream_t stream) {
  const float* conf = (const float*)d_in[0];
  const float* bbox = (const float*)d_in[1];
  const float* target = (const float*)d_in[2];
  const float* pred = (const float*)d_in[3];
  float* out = (float*)d_out;

  char* ws = (char*)d_ws;
  unsigned* keys = (unsigned*)ws;
  size_t off = (size_t)BN * 4;
  size_t zbase = off;
  unsigned long long* slab1 = (unsigned long long*)(ws + off); off += (size_t)NSLAB * NB1 * 8;
  unsigned long long* merged1 = (unsigned long long*)(ws + off); off += (size_t)NB1 * 8;
  unsigned long long* merged2 = (unsigned long long*)(ws + off); off += (size_t)R2 * NB2 * 8;
  Ctl2* ctl = (Ctl2*)(ws + off); off += 64;
  int nz = (int)((off - zbase) / 8);
  float4* batchCtl = (float4*)(ws + off); off += 64 * 16;  // written fully, no zero

  k_zero<<<64, 256, 0, stream>>>((unsigned long long*)(ws + zbase), nz);
  k_main<<<dim3(BPB, B), 256, 0, stream>>>(conf, bbox, target, pred, keys, slab1, batchCtl);
  k_pass2<<<P2B, 256, 0, stream>>>(keys, slab1, batchCtl, merged1, merged2, ctl, out);
}